// Round 2
// baseline (693.247 us; speedup 1.0000x reference)
//
#include <hip/hip_runtime.h>
#include <hip/hip_bf16.h>

// Problem constants
#define H       4096
#define BS      819        // diagonal block size
#define NB      5          // full diagonal blocks; o=h=4095 is a singleton
#define KPAD    832        // K per block padded to 26*32
#define NPAD    896        // N per block padded to 7*128
#define M_TOTAL 16384      // 8 * 2048
#define XB_LD   (NB * KPAD)   // 4160 bf16 per packed-x row
#define RS      40         // LDS row stride in bf16 elems (80 B -> bank-conflict-free)
#define TILE_CH 640        // 16B chunks per LDS tile (128 rows * 5 chunks/row)

// per-block front shift: makes packed index == global index (mod 4)
// shift_g = (3*g) & 3 ; data occupies [shift, shift+819) of the 832 slot
#define SHIFT(g) ((3 * (g)) & 3)

typedef __bf16 bf16x8 __attribute__((ext_vector_type(8)));
typedef float  f32x4  __attribute__((ext_vector_type(4)));

__device__ __forceinline__ void gld_lds16(const void* gptr, void* ldsptr) {
    __builtin_amdgcn_global_load_lds(
        (const __attribute__((address_space(1))) void*)gptr,
        (__attribute__((address_space(3))) void*)ldsptr,
        16, 0, 0);
}

// ---------------------------------------------------------------------------
// Pack x (fp32 [M][4096]) -> xb (bf16 [M][5*832]) with per-block front shift.
// Input-aligned: each thread does one aligned float4 read; thanks to the
// shift, the 4 bf16 outputs are 8B-aligned too (fast path). Block-boundary
// groups (5 per row) take the scalar path. blockIdx.x==4 zeroes the pads.
// ---------------------------------------------------------------------------
__global__ void pack_x_kernel(const float* __restrict__ x,
                              __hip_bfloat16* __restrict__ xb) {
    const int m = blockIdx.y;
    if (blockIdx.x == 4) {
        const int t = threadIdx.x;
        if (t < NB * 13) {                      // 13 pad elems per block
            const int g = t / 13, k = t % 13;
            const int shift = SHIFT(g);
            const int off = (k < shift) ? k : (BS + k);   // front pads then tail pads
            xb[(size_t)m * XB_LD + g * KPAD + off] = __float2bfloat16(0.f);
        }
        return;
    }
    const int q  = blockIdx.x * 256 + threadIdx.x;   // 0..1023
    const int j0 = q * 4;
    const float4 v = *reinterpret_cast<const float4*>(x + (size_t)m * H + j0);
    const int g0 = j0 / BS;
    const int g3 = (j0 + 3) / BS;
    if (g0 == g3) {
        const size_t o = (size_t)m * XB_LD + g0 * KPAD + SHIFT(g0) + (j0 - g0 * BS);
        union { __hip_bfloat16 h[4]; uint2 u; } tt;
        tt.h[0] = __float2bfloat16(v.x);
        tt.h[1] = __float2bfloat16(v.y);
        tt.h[2] = __float2bfloat16(v.z);
        tt.h[3] = __float2bfloat16(v.w);
        *reinterpret_cast<uint2*>(xb + o) = tt.u;
    } else {
        const float vv[4] = { v.x, v.y, v.z, v.w };
#pragma unroll
        for (int i = 0; i < 4; ++i) {
            const int j = j0 + i;
            if (j >= NB * BS) continue;          // elem 4095 -> singleton block
            const int g = j / BS;
            xb[(size_t)m * XB_LD + g * KPAD + SHIFT(g) + (j - g * BS)] =
                __float2bfloat16(vv[i]);
        }
    }
}

// ---------------------------------------------------------------------------
// Pack W block-diagonal -> wb (bf16 [5][896][832]) with matching front shift.
// ---------------------------------------------------------------------------
__global__ void pack_w_kernel(const float* __restrict__ W,
                              __hip_bfloat16* __restrict__ wb) {
    const int g  = blockIdx.y;
    const int p4 = (blockIdx.x * 256 + threadIdx.x) * 4;
    if (p4 >= NPAD * KPAD) return;
    const int n  = p4 / KPAD;
    const int k0 = p4 - n * KPAD;
    const int shift = SHIFT(g);
    union { __hip_bfloat16 h[4]; uint2 u; } tt;
#pragma unroll
    for (int i = 0; i < 4; ++i) {
        const int k = k0 + i - shift;
        float val = 0.f;
        if (n < BS && k >= 0 && k < BS)
            val = W[(size_t)(g * BS + n) * H + g * BS + k];
        tt.h[i] = __float2bfloat16(val);
    }
    *reinterpret_cast<uint2*>(wb + (size_t)g * NPAD * KPAD + p4) = tt.u;
}

// ---------------------------------------------------------------------------
// Singleton block: out[:,4095] = x[:,4095] * W[4095,4095]
// ---------------------------------------------------------------------------
__global__ void last_col_kernel(const float* __restrict__ x,
                                const float* __restrict__ W,
                                float* __restrict__ out) {
    const int m = blockIdx.x * blockDim.x + threadIdx.x;
    if (m >= M_TOTAL) return;
    const float w = W[(size_t)4095 * H + 4095];
    out[(size_t)m * H + 4095] = x[(size_t)m * H + 4095] * w;
}

// ---------------------------------------------------------------------------
// Block-diagonal bf16 GEMM, 128x128 tile, BK=32, mfma_f32_16x16x32_bf16.
// LDS row stride 80 B -> conflict-free fragment reads (start banks 20*l16+4q
// cover 8 disjoint 4-bank groups, 2 lanes each = free 2-way).
// Staging: 640 16B-chunks per tile; chunk c -> row c/5, k-byte (c%5)*16;
// c%5==4 chunks fall in the dead row pad (junk-filled from row 0).
// 1280 chunks total = 5 global_load_lds per thread, wave-contiguous.
// ---------------------------------------------------------------------------
__global__ void gemm_kernel(const __hip_bfloat16* __restrict__ xb,
                            const __hip_bfloat16* __restrict__ wb,
                            float* __restrict__ out) {
    __shared__ __hip_bfloat16 lA[128 * RS];   // 10240 B
    __shared__ __hip_bfloat16 lB[128 * RS];   // 10240 B

    const int tid   = threadIdx.x;
    const int mBase = blockIdx.x * 128;
    const int nBase = blockIdx.y * 128;
    const int g     = blockIdx.z;
    const int lane  = tid & 63;
    const int wave  = tid >> 6;
    const int waveM = wave >> 1;
    const int waveN = wave & 1;
    const int quad  = lane >> 4;
    const int l16   = lane & 15;
    (void)lane;

    const __hip_bfloat16* src[5];
    __hip_bfloat16*       dst[5];
#pragma unroll
    for (int s = 0; s < 5; ++s) {
        const int u   = tid + 256 * s;
        const bool isA = (u < TILE_CH);
        const int c   = isA ? u : (u - TILE_CH);
        const int r   = c / 5;
        const int rem = c - r * 5;
        const int rr  = (rem < 4) ? r : 0;       // pad chunks -> any valid row
        const int kk  = (rem < 4) ? rem * 8 : 0; // k-offset in elems
        src[s] = isA ? (xb + (size_t)(mBase + rr) * XB_LD + (size_t)g * KPAD + kk)
                     : (wb + ((size_t)g * NPAD + nBase + rr) * KPAD + kk);
        dst[s] = (isA ? lA : lB) + c * 8;        // c*16 bytes
    }

    f32x4 acc[4][4] = {};

    for (int kt = 0; kt < KPAD / 32; ++kt) {
        const int k0 = kt * 32;
#pragma unroll
        for (int s = 0; s < 5; ++s)
            gld_lds16(src[s] + k0, dst[s]);
        __syncthreads();

        bf16x8 a[4], b[4];
#pragma unroll
        for (int mi = 0; mi < 4; ++mi)
            a[mi] = *reinterpret_cast<const bf16x8*>(lA + (waveM * 64 + mi * 16 + l16) * RS + quad * 8);
#pragma unroll
        for (int ni = 0; ni < 4; ++ni)
            b[ni] = *reinterpret_cast<const bf16x8*>(lB + (waveN * 64 + ni * 16 + l16) * RS + quad * 8);

#pragma unroll
        for (int mi = 0; mi < 4; ++mi)
#pragma unroll
            for (int ni = 0; ni < 4; ++ni)
                acc[mi][ni] = __builtin_amdgcn_mfma_f32_16x16x32_bf16(a[mi], b[ni], acc[mi][ni], 0, 0, 0);
        __syncthreads();
    }

    // Epilogue: D row = quad*4 + r (m), col = l16 (n).
#pragma unroll
    for (int mi = 0; mi < 4; ++mi) {
        const int mrow = mBase + waveM * 64 + mi * 16 + quad * 4;
#pragma unroll
        for (int ni = 0; ni < 4; ++ni) {
            const int ncol = nBase + waveN * 64 + ni * 16 + l16;
            if (ncol < BS) {
                float* op = out + (size_t)mrow * H + (size_t)g * BS + ncol;
#pragma unroll
                for (int r = 0; r < 4; ++r)
                    op[(size_t)r * H] = acc[mi][ni][r];
            }
        }
    }
}

// ---------------------------------------------------------------------------
// Fallback (workspace too small): direct fp32, slow but correct.
// ---------------------------------------------------------------------------
__global__ void fallback_kernel(const float* __restrict__ x,
                                const float* __restrict__ W,
                                float* __restrict__ out) {
    const size_t idx = (size_t)blockIdx.x * blockDim.x + threadIdx.x;
    if (idx >= (size_t)M_TOTAL * H) return;
    const int m = (int)(idx / H);
    const int o = (int)(idx % H);
    const int g = o / BS;
    const int h0 = g * BS;
    const int len = (g < NB) ? BS : 1;
    const float* xr = x + (size_t)m * H + h0;
    const float* wr = W + (size_t)o * H + h0;
    float s = 0.f;
    for (int k = 0; k < len; ++k) s += xr[k] * wr[k];
    out[idx] = s;
}

extern "C" void kernel_launch(void* const* d_in, const int* in_sizes, int n_in,
                              void* d_out, int out_size, void* d_ws, size_t ws_size,
                              hipStream_t stream) {
    const float* x = (const float*)d_in[0];
    const float* W = (const float*)d_in[1];
    float* out = (float*)d_out;

    const size_t xb_elems = (size_t)M_TOTAL * XB_LD;
    const size_t wb_elems = (size_t)NB * NPAD * KPAD;
    const size_t need = (xb_elems + wb_elems) * sizeof(__hip_bfloat16);

    if (ws_size < need) {
        const size_t total = (size_t)M_TOTAL * H;
        fallback_kernel<<<(unsigned)((total + 255) / 256), 256, 0, stream>>>(x, W, out);
        return;
    }

    __hip_bfloat16* xb = (__hip_bfloat16*)d_ws;
    __hip_bfloat16* wb = xb + xb_elems;

    // grid.x: 4 data blocks (1024 float4 groups) + 1 pad-zero block
    pack_x_kernel<<<dim3(5, M_TOTAL), 256, 0, stream>>>(x, xb);
    pack_w_kernel<<<dim3((NPAD * KPAD / 4 + 255) / 256, NB), 256, 0, stream>>>(W, wb);
    gemm_kernel<<<dim3(M_TOTAL / 128, NPAD / 128, NB), 256, 0, stream>>>(xb, wb, out);
    last_col_kernel<<<(M_TOTAL + 255) / 256, 256, 0, stream>>>(x, W, out);
}